// Round 2
// baseline (164.551 us; speedup 1.0000x reference)
//
#include <hip/hip_runtime.h>

#define N_EDGES 8192
#define DD 256

typedef __attribute__((ext_vector_type(8))) short short8;
typedef __attribute__((ext_vector_type(8))) __bf16 bf16x8;
typedef __attribute__((ext_vector_type(4))) float floatx4;

__device__ __forceinline__ float bf2f(unsigned short u) {
  union { unsigned int i; float f; } v; v.i = ((unsigned int)u) << 16; return v.f;
}
__device__ __forceinline__ unsigned short f2bf(float f) {
  union { float f; unsigned int i; } v; v.f = f;
  unsigned int r = v.i + 0x7fffu + ((v.i >> 16) & 1u);
  return (unsigned short)(r >> 16);
}

__device__ __forceinline__ floatx4 mfma_bf16(short8 a, short8 b, floatx4 c) {
  bf16x8 av = __builtin_bit_cast(bf16x8, a);
  bf16x8 bv = __builtin_bit_cast(bf16x8, b);
  return __builtin_amdgcn_mfma_f32_16x16x32_bf16(av, bv, c, 0, 0, 0);
}

// ---------------------------------------------------------------------------
// zero G1,G2 (contiguous 512 KB of fp32)
__global__ void zero_g(float* __restrict__ g) {
  int idx = blockIdx.x * 256 + threadIdx.x;
  ((floatx4*)g)[idx] = (floatx4){0.f, 0.f, 0.f, 0.f};
}

// ---------------------------------------------------------------------------
// fp32 -> bf16 (RNE) for 4 tensors; blockIdx.y selects tensor; 8 elems/thread
__global__ void cvt4(const float* __restrict__ s0, unsigned short* __restrict__ d0, int n0,
                     const float* __restrict__ s1, unsigned short* __restrict__ d1, int n1,
                     const float* __restrict__ s2, unsigned short* __restrict__ d2, int n2,
                     const float* __restrict__ s3, unsigned short* __restrict__ d3, int n3) {
  const int t = blockIdx.y;
  const float* s = (t == 0) ? s0 : (t == 1) ? s1 : (t == 2) ? s2 : s3;
  unsigned short* d = (t == 0) ? d0 : (t == 1) ? d1 : (t == 2) ? d2 : d3;
  const int n8 = (t == 0) ? n0 : (t == 1) ? n1 : (t == 2) ? n2 : n3;
  int i = blockIdx.x * 256 + threadIdx.x;
  if (i >= n8) return;
  floatx4 a = ((const floatx4*)s)[2 * i];
  floatx4 b = ((const floatx4*)s)[2 * i + 1];
  short8 o;
#pragma unroll
  for (int k = 0; k < 4; ++k) { o[k] = (short)f2bf(a[k]); o[4 + k] = (short)f2bf(b[k]); }
  ((short8*)d)[i] = o;
}

// ---------------------------------------------------------------------------
// out[8192,256] = relu( sum_s A_s[8192,256](bf16) @ B_s[256,256](bf16) + bias(f32) )
// Block tile 128x128, 4 waves each 64x64 via 4x4 MFMA 16x16x32.
// blockIdx.z==1 switches (B0,bias,out) to the alt set (used to fuse e1/e2).
template <bool F32OUT>
__global__ __launch_bounds__(256, 2)
void gemm_bias_relu(const unsigned short* __restrict__ A0, const unsigned short* __restrict__ B0,
                    const unsigned short* __restrict__ A1, const unsigned short* __restrict__ B1,
                    const unsigned short* __restrict__ A2, const unsigned short* __restrict__ B2,
                    int nseg, const float* __restrict__ bias, void* __restrict__ outp,
                    const unsigned short* __restrict__ B0alt, const float* __restrict__ biasalt,
                    void* __restrict__ outalt)
{
  __shared__ unsigned short lds_a[128 * 40];   // [row][k] pad 40 (80B, 16B-aligned)
  __shared__ unsigned short lds_b[128 * 40];   // [m][k] transposed

  const unsigned short* B0s = B0;
  const float* bi = bias;
  void* op = outp;
  if (blockIdx.z) { B0s = B0alt; bi = biasalt; op = outalt; }

  const int tid  = threadIdx.x;
  const int lane = tid & 63;
  const int wave = tid >> 6;
  const int q = lane >> 4, r = lane & 15;
  const int wr = (wave >> 1) * 64;
  const int wc = (wave & 1) * 64;
  const int row0 = blockIdx.y * 128;
  const int col0 = blockIdx.x * 128;

  floatx4 acc[4][4];
#pragma unroll
  for (int i = 0; i < 4; ++i)
#pragma unroll
    for (int j = 0; j < 4; ++j) acc[i][j] = (floatx4){0.f, 0.f, 0.f, 0.f};

  const int ar = tid >> 1;           // A-stage row 0..127
  const int ak = (tid & 1) * 16;     // A-stage k offset {0,16}
  const int bk = tid >> 3;           // B-stage k row 0..31
  const int bg = tid & 7;            // B-stage m group
  const int bm = bg * 16;

  for (int s = 0; s < nseg; ++s) {
    const unsigned short* A = (s == 0) ? A0 : ((s == 1) ? A1 : A2);
    const unsigned short* B = (s == 0) ? B0s : ((s == 1) ? B1 : B2);
    for (int kc = 0; kc < 256; kc += 32) {
      const unsigned short* ga = A + (size_t)(row0 + ar) * DD + kc + ak;
      short8 av0 = *(const short8*)ga;
      short8 av1 = *(const short8*)(ga + 8);
      const unsigned short* gb = B + (size_t)(kc + bk) * DD + col0 + bm;
      short8 bv0 = *(const short8*)gb;
      short8 bv1 = *(const short8*)(gb + 8);

      *(short8*)&lds_a[ar * 40 + ak]     = av0;
      *(short8*)&lds_a[ar * 40 + ak + 8] = av1;
#pragma unroll
      for (int i = 0; i < 8; ++i) {       // transposed scalar writes, bank-swizzled
        int ii = (i + bk + bg) & 7;
        lds_b[(bm + ii) * 40 + bk]     = (unsigned short)bv0[ii];
        lds_b[(bm + 8 + ii) * 40 + bk] = (unsigned short)bv1[ii];
      }
      __syncthreads();

      short8 af[4], bfr[4];
#pragma unroll
      for (int i = 0; i < 4; ++i)
        af[i] = *(const short8*)&lds_a[(wr + i * 16 + r) * 40 + q * 8];
#pragma unroll
      for (int j = 0; j < 4; ++j)
        bfr[j] = *(const short8*)&lds_b[(wc + j * 16 + r) * 40 + q * 8];
#pragma unroll
      for (int i = 0; i < 4; ++i)
#pragma unroll
        for (int j = 0; j < 4; ++j)
          acc[i][j] = mfma_bf16(af[i], bfr[j], acc[i][j]);
      __syncthreads();
    }
  }

#pragma unroll
  for (int j = 0; j < 4; ++j) {
    const int col = col0 + wc + j * 16 + r;
    const float bv = bi[col];
#pragma unroll
    for (int i = 0; i < 4; ++i) {
      const int rowb = row0 + wr + i * 16 + q * 4;
#pragma unroll
      for (int t = 0; t < 4; ++t) {
        float v = acc[i][j][t] + bv;
        v = fmaxf(v, 0.0f);
        if (F32OUT) ((float*)op)[(size_t)(rowb + t) * DD + col] = v;
        else ((unsigned short*)op)[(size_t)(rowb + t) * DD + col] = f2bf(v);
      }
    }
  }
}

// ---------------------------------------------------------------------------
// G = e^T @ x  (256x256 fp32), split-K over j with fp32 atomics.
// grid: x in [0,4): 128x128 tile of G; y: split (256 j each); z: which (e,G).
__global__ __launch_bounds__(256, 2)
void atb_atomic(const unsigned short* __restrict__ e1w,
                const unsigned short* __restrict__ e2w,
                const unsigned short* __restrict__ x,
                float* __restrict__ G1, float* __restrict__ G2)
{
  __shared__ unsigned short lds_e[128 * 40];   // [m][j]
  __shared__ unsigned short lds_x[128 * 40];   // [n][j]

  const int tid  = threadIdx.x;
  const int lane = tid & 63;
  const int wave = tid >> 6;
  const int q = lane >> 4, r = lane & 15;
  const int wr = (wave >> 1) * 64, wc = (wave & 1) * 64;
  const int m0 = (blockIdx.x >> 1) * 128;
  const int n0 = (blockIdx.x & 1) * 128;
  const int j0 = blockIdx.y * 256;
  const unsigned short* E = blockIdx.z ? e2w : e1w;
  float* G = blockIdx.z ? G2 : G1;

  floatx4 acc[4][4];
#pragma unroll
  for (int i = 0; i < 4; ++i)
#pragma unroll
    for (int j = 0; j < 4; ++j) acc[i][j] = (floatx4){0.f, 0.f, 0.f, 0.f};

  const int jr = tid >> 3;   // 0..31
  const int gg = tid & 7;
  const int mg = gg * 16;

  for (int jc = 0; jc < 256; jc += 32) {
    const int jrow = j0 + jc + jr;
    const unsigned short* ge = E + (size_t)jrow * DD + m0 + mg;
    short8 ev0 = *(const short8*)ge;
    short8 ev1 = *(const short8*)(ge + 8);
    const unsigned short* gx = x + (size_t)jrow * DD + n0 + mg;
    short8 xv0 = *(const short8*)gx;
    short8 xv1 = *(const short8*)(gx + 8);
#pragma unroll
    for (int i = 0; i < 8; ++i) {
      int ii = (i + jr + gg) & 7;
      lds_e[(mg + ii) * 40 + jr]     = (unsigned short)ev0[ii];
      lds_e[(mg + 8 + ii) * 40 + jr] = (unsigned short)ev1[ii];
      lds_x[(mg + ii) * 40 + jr]     = (unsigned short)xv0[ii];
      lds_x[(mg + 8 + ii) * 40 + jr] = (unsigned short)xv1[ii];
    }
    __syncthreads();

    short8 af[4], bfr[4];
#pragma unroll
    for (int i = 0; i < 4; ++i)
      af[i] = *(const short8*)&lds_e[(wr + i * 16 + r) * 40 + q * 8];
#pragma unroll
    for (int j = 0; j < 4; ++j)
      bfr[j] = *(const short8*)&lds_x[(wc + j * 16 + r) * 40 + q * 8];
#pragma unroll
    for (int i = 0; i < 4; ++i)
#pragma unroll
      for (int j = 0; j < 4; ++j)
        acc[i][j] = mfma_bf16(af[i], bfr[j], acc[i][j]);
    __syncthreads();
  }

#pragma unroll
  for (int i = 0; i < 4; ++i) {
#pragma unroll
    for (int j = 0; j < 4; ++j) {
      const int n = n0 + wc + j * 16 + r;
#pragma unroll
      for (int t = 0; t < 4; ++t) {
        const int m = m0 + wr + i * 16 + q * 4 + t;
        unsafeAtomicAdd(&G[m * 256 + n], acc[i][j][t]);
      }
    }
  }
}

// ---------------------------------------------------------------------------
// H_z[256,256](bf16) = (G_z / 256) @ W3b[256+z*256 : 512+z*256, :]  (W3b bf16)
__global__ __launch_bounds__(256, 2)
void h_kernel(const float* __restrict__ G1, const float* __restrict__ G2,
              const unsigned short* __restrict__ W3b,
              unsigned short* __restrict__ H1, unsigned short* __restrict__ H2)
{
  __shared__ float lg[64 * 36];   // [k][l]
  __shared__ float lw[32 * 68];   // [l][m]
  const int z = blockIdx.z;
  const float* G = z ? G2 : G1;
  unsigned short* H = z ? H2 : H1;
  const unsigned short* Wb = W3b + (size_t)(256 + z * 256) * DD;
  const int k0 = blockIdx.y * 64;
  const int m0 = blockIdx.x * 64;
  const int tid = threadIdx.x;
  const int ty = tid >> 4, tx = tid & 15;

  float acc[4][4] = {};

  for (int lc = 0; lc < 256; lc += 32) {
    {
      int kr = tid >> 2;            // 0..63
      int l8 = (tid & 3) * 8;
      const float* gp = G + (size_t)(k0 + kr) * 256 + lc + l8;
      floatx4 g0 = *(const floatx4*)gp;
      floatx4 g1 = *(const floatx4*)(gp + 4);
      *(floatx4*)&lg[kr * 36 + l8]     = g0;
      *(floatx4*)&lg[kr * 36 + l8 + 4] = g1;
    }
    {
      int lr = tid >> 3;            // 0..31
      int m8 = (tid & 7) * 8;
      const unsigned short* wp = Wb + (size_t)(lc + lr) * DD + m0 + m8;
      short8 wv = *(const short8*)wp;
#pragma unroll
      for (int i = 0; i < 8; ++i) lw[lr * 68 + m8 + i] = bf2f((unsigned short)wv[i]);
    }
    __syncthreads();
#pragma unroll
    for (int l = 0; l < 32; ++l) {
      float a[4], b[4];
#pragma unroll
      for (int i = 0; i < 4; ++i) a[i] = lg[(ty * 4 + i) * 36 + l];
#pragma unroll
      for (int j = 0; j < 4; ++j) b[j] = lw[l * 68 + tx * 4 + j];
#pragma unroll
      for (int i = 0; i < 4; ++i)
#pragma unroll
        for (int j = 0; j < 4; ++j) acc[i][j] = fmaf(a[i], b[j], acc[i][j]);
    }
    __syncthreads();
  }
#pragma unroll
  for (int i = 0; i < 4; ++i)
#pragma unroll
    for (int j = 0; j < 4; ++j)
      H[(size_t)(k0 + ty * 4 + i) * DD + m0 + tx * 4 + j] = f2bf(acc[i][j] * 0.00390625f);
}

// ---------------------------------------------------------------------------
extern "C" void kernel_launch(void* const* d_in, const int* in_sizes, int n_in,
                              void* d_out, int out_size, void* d_ws, size_t ws_size,
                              hipStream_t stream) {
  (void)in_sizes; (void)n_in; (void)out_size; (void)ws_size;
  const float* x   = (const float*)d_in[3];
  const float* W1  = (const float*)d_in[5];
  const float* b1  = (const float*)d_in[6];
  const float* W2  = (const float*)d_in[7];
  const float* b2  = (const float*)d_in[8];
  const float* W3  = (const float*)d_in[9];
  const float* b3  = (const float*)d_in[10];
  float* out = (float*)d_out;

  char* ws = (char*)d_ws;
  const size_t MB = 1u << 20;
  const size_t KB = 1u << 10;
  unsigned short* xb  = (unsigned short*)ws;                              // 4 MB
  unsigned short* e1  = (unsigned short*)(ws + 4 * MB);                   // 4 MB
  unsigned short* e2  = (unsigned short*)(ws + 8 * MB);                   // 4 MB
  float* G1           = (float*)(ws + 12 * MB);                           // 256 KB
  float* G2           = (float*)(ws + 12 * MB + 256 * KB);                // 256 KB
  unsigned short* H1  = (unsigned short*)(ws + 12 * MB + 512 * KB);       // 128 KB
  unsigned short* H2  = (unsigned short*)(ws + 12 * MB + 640 * KB);       // 128 KB
  unsigned short* W1b = (unsigned short*)(ws + 12 * MB + 768 * KB);       // 128 KB
  unsigned short* W2b = (unsigned short*)(ws + 12 * MB + 896 * KB);       // 128 KB
  unsigned short* W3b = (unsigned short*)(ws + 13 * MB);                  // 384 KB

  zero_g<<<128, 256, 0, stream>>>(G1);  // covers G1+G2 (contiguous 512 KB)

  cvt4<<<dim3(1024, 4), 256, 0, stream>>>(
      x,  xb,  (N_EDGES * DD) / 8,
      W1, W1b, (DD * DD) / 8,
      W2, W2b, (DD * DD) / 8,
      W3, W3b, (3 * DD * DD) / 8);

  // e1 = relu(x@W1+b1) and e2 = relu(x@W2+b2), fused via gridDim.z
  gemm_bias_relu<false><<<dim3(2, 64, 2), 256, 0, stream>>>(
      xb, W1b, nullptr, nullptr, nullptr, nullptr, 1, b1, e1, W2b, b2, e2);

  atb_atomic<<<dim3(4, 32, 2), 256, 0, stream>>>(e1, e2, xb, G1, G2);

  h_kernel<<<dim3(4, 4, 2), 256, 0, stream>>>(G1, G2, W3b, H1, H2);

  // out = relu( x@W3[0:256] + e1@H1 + e2@H2 + b3 )  (fp32 out)
  gemm_bias_relu<true><<<dim3(2, 64, 1), 256, 0, stream>>>(
      xb, W3b, e1, H1, e2, H2, 3, b3, out, nullptr, nullptr, nullptr);
}

// Round 3
// 144.688 us; speedup vs baseline: 1.1373x; 1.1373x over previous
//
#include <hip/hip_runtime.h>

#define NE 8192
#define DD 256
#define NSPLIT 32

typedef __attribute__((ext_vector_type(8))) short short8;
typedef __attribute__((ext_vector_type(4))) short short4v;
typedef __attribute__((ext_vector_type(8))) __bf16 bf16x8;
typedef __attribute__((ext_vector_type(4))) float floatx4;

__device__ __forceinline__ unsigned short f2bf(float f) {
  union { float f; unsigned int i; } v; v.f = f;
  unsigned int r = v.i + 0x7fffu + ((v.i >> 16) & 1u);
  return (unsigned short)(r >> 16);
}

__device__ __forceinline__ floatx4 mfma_bf16(short8 a, short8 b, floatx4 c) {
  return __builtin_amdgcn_mfma_f32_16x16x32_bf16(
      __builtin_bit_cast(bf16x8, a), __builtin_bit_cast(bf16x8, b), c, 0, 0, 0);
}

// ---------------------------------------------------------------------------
// cvt_all: one kernel, block-range dispatch.
//   [0,1024)        : straight fp32->bf16 of x (8192x256) -> xb
//   [1024,1536)     : transpose-cvt x -> xT (256x8192 bf16), 64x64 tiles
//   [1536,1552)     : transpose-cvt W1 (256x256) -> W1t
//   [1552,1568)     : transpose-cvt W2 -> W2t
//   [1568,1584)     : transpose-cvt W3[0:256] -> W3t0
__device__ __forceinline__ void tcvt_tile(const float* __restrict__ src, int C,
                                          unsigned short* __restrict__ dst, int R,
                                          int r0, int c0, int tid) {
  __shared__ float ls[64][68];
  const int rr = tid >> 4;            // 0..15
  const int c4 = (tid & 15) * 4;
#pragma unroll
  for (int k = 0; k < 4; ++k) {
    floatx4 v = *(const floatx4*)&src[(size_t)(r0 + rr + k * 16) * C + c0 + c4];
    *(floatx4*)&ls[rr + k * 16][c4] = v;
  }
  __syncthreads();
  const int cc = tid >> 2;            // 0..63
  const int rb = (tid & 3) * 16;
  short8 o0, o1;
#pragma unroll
  for (int i = 0; i < 8; ++i) {
    o0[i] = (short)f2bf(ls[rb + i][cc]);
    o1[i] = (short)f2bf(ls[rb + 8 + i][cc]);
  }
  unsigned short* dp = &dst[(size_t)(c0 + cc) * R + r0 + rb];
  *(short8*)dp = o0;
  *(short8*)(dp + 8) = o1;
}

__global__ void cvt_all(const float* __restrict__ x, unsigned short* __restrict__ xb,
                        unsigned short* __restrict__ xT,
                        const float* __restrict__ W1, unsigned short* __restrict__ W1t,
                        const float* __restrict__ W2, unsigned short* __restrict__ W2t,
                        const float* __restrict__ W3, unsigned short* __restrict__ W3t0) {
  const int b = blockIdx.x;
  const int tid = threadIdx.x;
  if (b < 1024) {                     // straight cvt, 8 elems/thread
    int i = b * 256 + tid;
    floatx4 a = ((const floatx4*)x)[2 * i];
    floatx4 c = ((const floatx4*)x)[2 * i + 1];
    short8 o;
#pragma unroll
    for (int k = 0; k < 4; ++k) { o[k] = (short)f2bf(a[k]); o[4 + k] = (short)f2bf(c[k]); }
    ((short8*)xb)[i] = o;
  } else if (b < 1536) {              // x transpose: 128 x 4 tiles
    int t = b - 1024;
    tcvt_tile(x, DD, xT, NE, (t >> 2) * 64, (t & 3) * 64, tid);
  } else if (b < 1552) {
    int t = b - 1536;
    tcvt_tile(W1, DD, W1t, DD, (t >> 2) * 64, (t & 3) * 64, tid);
  } else if (b < 1568) {
    int t = b - 1552;
    tcvt_tile(W2, DD, W2t, DD, (t >> 2) * 64, (t & 3) * 64, tid);
  } else {
    int t = b - 1568;
    tcvt_tile(W3, DD, W3t0, DD, (t >> 2) * 64, (t & 3) * 64, tid);
  }
}

// ---------------------------------------------------------------------------
// out[8192,256] = relu( sum_s A_s[8192,256](bf16,row-major) @ B_s^T + bias )
// B_s given TRANSPOSED: [n][k] bf16. Block tile 128x128, 4 waves 64x64 each.
// blockIdx.z==1 switches (B0,bias,out,outT) to alt set (fuses e1/e2).
// STORE_T: additionally store out^T [col][row] bf16 (vectorized short4).
template <bool F32OUT, bool STORE_T>
__global__ __launch_bounds__(256, 2)
void gemm_bias_relu(const unsigned short* __restrict__ A0, const unsigned short* __restrict__ B0,
                    const unsigned short* __restrict__ A1, const unsigned short* __restrict__ B1,
                    const unsigned short* __restrict__ A2, const unsigned short* __restrict__ B2,
                    int nseg, const float* __restrict__ bias, void* __restrict__ outp,
                    unsigned short* __restrict__ outT,
                    const unsigned short* __restrict__ B0alt, const float* __restrict__ biasalt,
                    void* __restrict__ outalt, unsigned short* __restrict__ outTalt)
{
  __shared__ unsigned short lds_a[128 * 40];   // [row][k], pad 40 shorts (80B)
  __shared__ unsigned short lds_b[128 * 40];   // [n][k]

  const unsigned short* B0s = B0;
  const float* bi = bias;
  void* op = outp;
  unsigned short* ot = outT;
  if (blockIdx.z) { B0s = B0alt; bi = biasalt; op = outalt; ot = outTalt; }

  const int tid  = threadIdx.x;
  const int lane = tid & 63;
  const int wave = tid >> 6;
  const int q = lane >> 4, r = lane & 15;
  const int wr = (wave >> 1) * 64;
  const int wc = (wave & 1) * 64;
  const int row0 = blockIdx.y * 128;
  const int col0 = blockIdx.x * 128;

  floatx4 acc[4][4];
#pragma unroll
  for (int i = 0; i < 4; ++i)
#pragma unroll
    for (int j = 0; j < 4; ++j) acc[i][j] = (floatx4){0.f, 0.f, 0.f, 0.f};

  const int sr = tid >> 1;           // staging row 0..127
  const int sk = (tid & 1) * 16;     // staging k offset {0,16}

  for (int s = 0; s < nseg; ++s) {
    const unsigned short* A = (s == 0) ? A0 : ((s == 1) ? A1 : A2);
    const unsigned short* B = (s == 0) ? B0s : ((s == 1) ? B1 : B2);
    for (int kc = 0; kc < 256; kc += 32) {
      const unsigned short* ga = A + (size_t)(row0 + sr) * DD + kc + sk;
      short8 av0 = *(const short8*)ga;
      short8 av1 = *(const short8*)(ga + 8);
      const unsigned short* gb = B + (size_t)(col0 + sr) * DD + kc + sk;
      short8 bv0 = *(const short8*)gb;
      short8 bv1 = *(const short8*)(gb + 8);

      *(short8*)&lds_a[sr * 40 + sk]     = av0;
      *(short8*)&lds_a[sr * 40 + sk + 8] = av1;
      *(short8*)&lds_b[sr * 40 + sk]     = bv0;
      *(short8*)&lds_b[sr * 40 + sk + 8] = bv1;
      __syncthreads();

      short8 af[4], bfr[4];
#pragma unroll
      for (int i = 0; i < 4; ++i)
        af[i] = *(const short8*)&lds_a[(wr + i * 16 + r) * 40 + q * 8];
#pragma unroll
      for (int j = 0; j < 4; ++j)
        bfr[j] = *(const short8*)&lds_b[(wc + j * 16 + r) * 40 + q * 8];
#pragma unroll
      for (int i = 0; i < 4; ++i)
#pragma unroll
        for (int j = 0; j < 4; ++j)
          acc[i][j] = mfma_bf16(af[i], bfr[j], acc[i][j]);
      __syncthreads();
    }
  }

#pragma unroll
  for (int j = 0; j < 4; ++j) {
    const int col = col0 + wc + j * 16 + r;
    const float bv = bi[col];
#pragma unroll
    for (int i = 0; i < 4; ++i) {
      const int rowb = row0 + wr + i * 16 + q * 4;
      float v[4];
#pragma unroll
      for (int t = 0; t < 4; ++t) v[t] = fmaxf(acc[i][j][t] + bv, 0.0f);
      if (F32OUT) {
#pragma unroll
        for (int t = 0; t < 4; ++t)
          ((float*)op)[(size_t)(rowb + t) * DD + col] = v[t];
      } else {
#pragma unroll
        for (int t = 0; t < 4; ++t)
          ((unsigned short*)op)[(size_t)(rowb + t) * DD + col] = f2bf(v[t]);
      }
      if (STORE_T) {
        short4v tv;
#pragma unroll
        for (int t = 0; t < 4; ++t) tv[t] = (short)f2bf(v[t]);
        *(short4v*)&ot[(size_t)col * NE + rowb] = tv;
      }
    }
  }
}

// ---------------------------------------------------------------------------
// Partial G^T: P_T[z*NSPLIT+y][n][m] += slice. A = e_z^T [m][j], B = x^T [n][j],
// both bf16 row-major over j (stride NE). No atomics: each (z,y) buffer's
// quadrants written by disjoint blocks, vectorized floatx4 stores.
__global__ __launch_bounds__(256, 2)
void atb_partial(const unsigned short* __restrict__ e1T,
                 const unsigned short* __restrict__ e2T,
                 const unsigned short* __restrict__ xT,
                 float* __restrict__ P_T)
{
  __shared__ unsigned short lds_e[128 * 40];
  __shared__ unsigned short lds_x[128 * 40];

  const int tid  = threadIdx.x;
  const int lane = tid & 63;
  const int wave = tid >> 6;
  const int q = lane >> 4, r = lane & 15;
  const int wr = (wave >> 1) * 64, wc = (wave & 1) * 64;
  const int m0 = (blockIdx.x >> 1) * 128;
  const int n0 = (blockIdx.x & 1) * 128;
  const int j0 = blockIdx.y * (NE / NSPLIT);
  const unsigned short* E = blockIdx.z ? e2T : e1T;
  float* P = P_T + (size_t)(blockIdx.z * NSPLIT + blockIdx.y) * 65536;

  floatx4 acc[4][4];
#pragma unroll
  for (int i = 0; i < 4; ++i)
#pragma unroll
    for (int j = 0; j < 4; ++j) acc[i][j] = (floatx4){0.f, 0.f, 0.f, 0.f};

  const int sr = tid >> 1;
  const int sk = (tid & 1) * 16;

  for (int jc = 0; jc < NE / NSPLIT; jc += 32) {
    const unsigned short* ge = E + (size_t)(m0 + sr) * NE + j0 + jc + sk;
    short8 ev0 = *(const short8*)ge;
    short8 ev1 = *(const short8*)(ge + 8);
    const unsigned short* gx = xT + (size_t)(n0 + sr) * NE + j0 + jc + sk;
    short8 xv0 = *(const short8*)gx;
    short8 xv1 = *(const short8*)(gx + 8);
    *(short8*)&lds_e[sr * 40 + sk]     = ev0;
    *(short8*)&lds_e[sr * 40 + sk + 8] = ev1;
    *(short8*)&lds_x[sr * 40 + sk]     = xv0;
    *(short8*)&lds_x[sr * 40 + sk + 8] = xv1;
    __syncthreads();

    short8 af[4], bfr[4];
#pragma unroll
    for (int i = 0; i < 4; ++i)
      af[i] = *(const short8*)&lds_e[(wr + i * 16 + r) * 40 + q * 8];
#pragma unroll
    for (int j = 0; j < 4; ++j)
      bfr[j] = *(const short8*)&lds_x[(wc + j * 16 + r) * 40 + q * 8];
#pragma unroll
    for (int i = 0; i < 4; ++i)
#pragma unroll
      for (int j = 0; j < 4; ++j)
        acc[i][j] = mfma_bf16(af[i], bfr[j], acc[i][j]);
    __syncthreads();
  }

#pragma unroll
  for (int i = 0; i < 4; ++i)
#pragma unroll
    for (int j = 0; j < 4; ++j) {
      const int n = n0 + wc + j * 16 + r;
      const int m = m0 + wr + i * 16 + q * 4;
      *(floatx4*)&P[(size_t)n * DD + m] = acc[i][j];
    }
}

// ---------------------------------------------------------------------------
// G_T[z][n][m] = sum_y P_T[z*NSPLIT+y][n][m]. 128 blocks x 256 thr, f4 each.
__global__ void reduce_g(const float* __restrict__ P_T, float* __restrict__ G_T) {
  int idx = blockIdx.x * 256 + threadIdx.x;          // 0..32767 (f4 index)
  int z = idx >> 14;
  int off = idx & 16383;
  const floatx4* Pp = (const floatx4*)P_T;
  floatx4 s = (floatx4){0.f, 0.f, 0.f, 0.f};
#pragma unroll
  for (int y = 0; y < NSPLIT; ++y)
    s += Pp[(size_t)(z * NSPLIT + y) * 16384 + off];
  ((floatx4*)G_T)[idx] = s;
}

// ---------------------------------------------------------------------------
// H_t[z][m][k] = transpose of H_z = (G_z/256) @ W3[256+z*256 : 512+z*256, :]
// G given as G_T[z][l][k] f32; W3 fp32 [l][m]. Both staged l-major, vectorized.
__global__ __launch_bounds__(256, 2)
void h_kernel(const float* __restrict__ G_T, const float* __restrict__ W3,
              unsigned short* __restrict__ H1t, unsigned short* __restrict__ H2t)
{
  __shared__ float lg[32 * 68];   // [l][k-tile]
  __shared__ float lw[32 * 68];   // [l][m-tile]
  const int z = blockIdx.z;
  const float* G = G_T + (size_t)z * 65536;
  unsigned short* Ht = z ? H2t : H1t;
  const float* Wb = W3 + (size_t)(256 + z * 256) * DD;
  const int k0 = blockIdx.y * 64;
  const int m0 = blockIdx.x * 64;
  const int tid = threadIdx.x;
  const int ty = tid >> 4, tx = tid & 15;

  float acc[4][4] = {};

  for (int lc = 0; lc < 256; lc += 32) {
    {
      int lr = tid >> 3;            // 0..31
      int e8 = (tid & 7) * 8;
      const float* gp = G + (size_t)(lc + lr) * DD + k0 + e8;
      *(floatx4*)&lg[lr * 68 + e8]     = *(const floatx4*)gp;
      *(floatx4*)&lg[lr * 68 + e8 + 4] = *(const floatx4*)(gp + 4);
      const float* wp = Wb + (size_t)(lc + lr) * DD + m0 + e8;
      *(floatx4*)&lw[lr * 68 + e8]     = *(const floatx4*)wp;
      *(floatx4*)&lw[lr * 68 + e8 + 4] = *(const floatx4*)(wp + 4);
    }
    __syncthreads();
#pragma unroll
    for (int l = 0; l < 32; ++l) {
      float a[4], b[4];
#pragma unroll
      for (int i = 0; i < 4; ++i) a[i] = lg[l * 68 + ty * 4 + i];
#pragma unroll
      for (int j = 0; j < 4; ++j) b[j] = lw[l * 68 + tx * 4 + j];
#pragma unroll
      for (int i = 0; i < 4; ++i)
#pragma unroll
        for (int j = 0; j < 4; ++j) acc[i][j] = fmaf(a[i], b[j], acc[i][j]);
    }
    __syncthreads();
  }
#pragma unroll
  for (int j = 0; j < 4; ++j) {
    short4v tv;
#pragma unroll
    for (int i = 0; i < 4; ++i) tv[i] = (short)f2bf(acc[i][j] * 0.00390625f);
    *(short4v*)&Ht[(size_t)(m0 + tx * 4 + j) * DD + k0 + ty * 4] = tv;
  }
}

// ---------------------------------------------------------------------------
extern "C" void kernel_launch(void* const* d_in, const int* in_sizes, int n_in,
                              void* d_out, int out_size, void* d_ws, size_t ws_size,
                              hipStream_t stream) {
  (void)in_sizes; (void)n_in; (void)out_size; (void)ws_size;
  const float* x   = (const float*)d_in[3];
  const float* W1  = (const float*)d_in[5];
  const float* b1  = (const float*)d_in[6];
  const float* W2  = (const float*)d_in[7];
  const float* b2  = (const float*)d_in[8];
  const float* W3  = (const float*)d_in[9];
  const float* b3  = (const float*)d_in[10];
  float* out = (float*)d_out;

  char* ws = (char*)d_ws;
  const size_t MB = 1u << 20;
  const size_t KB = 1u << 10;
  unsigned short* xb   = (unsigned short*)ws;                          // 4 MB
  unsigned short* xT   = (unsigned short*)(ws + 4 * MB);               // 4 MB
  unsigned short* e1   = (unsigned short*)(ws + 8 * MB);               // 4 MB
  unsigned short* e2   = (unsigned short*)(ws + 12 * MB);              // 4 MB
  unsigned short* e1T  = (unsigned short*)(ws + 16 * MB);              // 4 MB
  unsigned short* e2T  = (unsigned short*)(ws + 20 * MB);              // 4 MB
  unsigned short* W1t  = (unsigned short*)(ws + 24 * MB);              // 128 KB
  unsigned short* W2t  = (unsigned short*)(ws + 24 * MB + 128 * KB);   // 128 KB
  unsigned short* W3t0 = (unsigned short*)(ws + 24 * MB + 256 * KB);   // 128 KB
  unsigned short* H1t  = (unsigned short*)(ws + 24 * MB + 384 * KB);   // 128 KB
  unsigned short* H2t  = (unsigned short*)(ws + 24 * MB + 512 * KB);   // 128 KB
  float* G_T           = (float*)(ws + 24 * MB + 640 * KB);            // 512 KB
  float* P_T           = (float*)(ws + 26 * MB);                       // 16 MB

  cvt_all<<<1584, 256, 0, stream>>>(x, xb, xT, W1, W1t, W2, W2t, W3, W3t0);

  // e1 = relu(x@W1+b1), e2 = relu(x@W2+b2); also emit e^T (fused via z)
  gemm_bias_relu<false, true><<<dim3(2, 64, 2), 256, 0, stream>>>(
      xb, W1t, nullptr, nullptr, nullptr, nullptr, 1, b1, e1, e1T, W2t, b2, e2, e2T);

  atb_partial<<<dim3(4, NSPLIT, 2), 256, 0, stream>>>(e1T, e2T, xT, P_T);
  reduce_g<<<128, 256, 0, stream>>>(P_T, G_T);

  h_kernel<<<dim3(4, 4, 2), 256, 0, stream>>>(G_T, W3, H1t, H2t);

  // out = relu( x@W3[0:256] + e1@H1 + e2@H2 + b3 )  (fp32 out)
  gemm_bias_relu<true, false><<<dim3(2, 64, 1), 256, 0, stream>>>(
      xb, W3t0, e1, H1t, e2, H2t, 3, b3, out, nullptr, nullptr, nullptr, nullptr, nullptr);
}